// Round 1
// baseline (459.243 us; speedup 1.0000x reference)
//
#include <hip/hip_runtime.h>
#include <hip/hip_bf16.h>

// Problem constants
#define VN 10000
#define HID 128
// W1 rows (161 x 128): [0,64) Wh, [64,128) Wm, 128 Wt, [129,161) Wp

using bf16x8 = __attribute__((ext_vector_type(8))) __bf16;
using bf16x4 = __attribute__((ext_vector_type(4))) __bf16;
using f32x4  = __attribute__((ext_vector_type(4))) float;

// ---------------------------------------------------------------------------
// prep_kernel:
//   blocks [0,625): base[v][h] = b1[h] + h_t[v]@Wh + theta[v]@Wp   (fp32)
//   blocks [625,657): wmt[n*64+d] = bf16(Wm[d][n])  (transposed, n-major)
// ---------------------------------------------------------------------------
__global__ __launch_bounds__(256) void prep_kernel(
    const float* __restrict__ h_t, const float* __restrict__ theta,
    const float* __restrict__ W1, const float* __restrict__ b1,
    float* __restrict__ base, __bf16* __restrict__ wmt)
{
  const int blk = blockIdx.x;
  const int tid = threadIdx.x;
  if (blk < 625) {
    __shared__ float in[16][96];   // 16 nodes x (64 h_t | 32 theta)
    const int v0 = blk * 16;
    {
      // h_t: 16 rows x 64 floats = 256 float4
      const float4* src = (const float4*)(h_t + (size_t)v0 * 64);
      float4 f = src[tid];
      int vl = tid >> 4, c = (tid & 15) * 4;
      in[vl][c] = f.x; in[vl][c + 1] = f.y; in[vl][c + 2] = f.z; in[vl][c + 3] = f.w;
    }
    if (tid < 128) {
      // theta: 16 rows x 32 floats = 128 float4
      const float4* src = (const float4*)(theta + (size_t)v0 * 32);
      float4 f = src[tid];
      int vl = tid >> 3, c = 64 + (tid & 7) * 4;
      in[vl][c] = f.x; in[vl][c + 1] = f.y; in[vl][c + 2] = f.z; in[vl][c + 3] = f.w;
    }
    __syncthreads();
    const int h = tid & 127;
    const int half = tid >> 7;      // wave-uniform
    float acc[8];
    const float bb = b1[h];
    #pragma unroll
    for (int k = 0; k < 8; k++) acc[k] = bb;
    for (int d = 0; d < 64; d++) {
      float w = W1[d * 128 + h];                 // Wh row d
      #pragma unroll
      for (int k = 0; k < 8; k++) acc[k] += in[2 * k + half][d] * w;
    }
    for (int d = 0; d < 32; d++) {
      float w = W1[(129 + d) * 128 + h];         // Wp row d
      #pragma unroll
      for (int k = 0; k < 8; k++) acc[k] += in[2 * k + half][64 + d] * w;
    }
    #pragma unroll
    for (int k = 0; k < 8; k++)
      base[(size_t)(v0 + 2 * k + half) * 128 + h] = acc[k];
  } else {
    int j = (blk - 625) * 256 + tid;   // 32 blocks * 256 = 8192 exact
    int n = j >> 6, d = j & 63;
    wmt[j] = (__bf16)W1[(64 + d) * 128 + n];     // Wm^T[n][d]
  }
}

// ---------------------------------------------------------------------------
// main_kernel: one block per node v (grid = 10000, 256 threads = 4 waves)
//   hidden(128x128) = bf16(messages[v]) (128x64) @ Wm (64x128), + base + tau*Wt
//   logits[v][m] = relu(hidden[m]) @ W2 + b2
// ---------------------------------------------------------------------------
__global__ __launch_bounds__(256) void main_kernel(
    const float* __restrict__ messages, const float* __restrict__ tau,
    const float* __restrict__ W1, const float* __restrict__ W2,
    const float* __restrict__ b2, const float* __restrict__ base,
    const __bf16* __restrict__ wmt, float* __restrict__ out)
{
  // pad 64 -> 72 bf16 (144 B rows): keeps 16B alignment for b128, breaks the
  // 128B (=32 bank) stride so quad-groups land on rotating bank sets
  __shared__ __align__(16) __bf16 lA[128 * 72];
  __shared__ __align__(16) __bf16 lB[128 * 72];
  __shared__ float lOut[128];

  const int v = blockIdx.x;
  const int tid = threadIdx.x;
  const int w = tid >> 6;
  const int lane = tid & 63;
  const int quad = lane >> 4;
  const int l16 = lane & 15;

  // ---- stage A: messages[v] (128x64 f32) -> bf16 LDS ----
  {
    const float4* src = (const float4*)(messages + (size_t)v * 8192);
    #pragma unroll
    for (int j = 0; j < 8; j++) {
      int idx = j * 256 + tid;          // 2048 float4
      float4 f = src[idx];
      int r = idx >> 4, c = (idx & 15) * 4;
      bf16x4 p;
      p[0] = (__bf16)f.x; p[1] = (__bf16)f.y; p[2] = (__bf16)f.z; p[3] = (__bf16)f.w;
      *(bf16x4*)&lA[r * 72 + c] = p;
    }
  }
  // ---- stage B: Wm^T bf16 (128x64) ----
  {
    const uint4* src = (const uint4*)wmt;
    #pragma unroll
    for (int j = 0; j < 4; j++) {
      int idx = j * 256 + tid;          // 1024 uint4
      uint4 u = src[idx];
      int r = idx >> 3, c = (idx & 7) * 8;
      *(uint4*)&lB[r * 72 + c] = u;
    }
  }
  __syncthreads();

  // ---- MFMA: wave w covers rows [32w, 32w+32), all 128 cols ----
  f32x4 acc[2][8];
  #pragma unroll
  for (int mt = 0; mt < 2; mt++)
    #pragma unroll
    for (int nt = 0; nt < 8; nt++) acc[mt][nt] = (f32x4){0.f, 0.f, 0.f, 0.f};

  #pragma unroll
  for (int ks = 0; ks < 2; ks++) {
    const int k = ks * 32 + quad * 8;
    bf16x8 a[2], b[8];
    #pragma unroll
    for (int mt = 0; mt < 2; mt++) {
      int m = 32 * w + mt * 16 + l16;
      a[mt] = *(const bf16x8*)&lA[m * 72 + k];
    }
    #pragma unroll
    for (int nt = 0; nt < 8; nt++) {
      int n = nt * 16 + l16;
      b[nt] = *(const bf16x8*)&lB[n * 72 + k];
    }
    #pragma unroll
    for (int mt = 0; mt < 2; mt++)
      #pragma unroll
      for (int nt = 0; nt < 8; nt++)
        acc[mt][nt] = __builtin_amdgcn_mfma_f32_16x16x32_bf16(a[mt], b[nt], acc[mt][nt], 0, 0, 0);
  }

  // ---- epilogue: + base + tau*Wt, relu, @W2, reduce over n ----
  float bb[8], w2[8], wt[8];
  #pragma unroll
  for (int nt = 0; nt < 8; nt++) {
    int n = nt * 16 + l16;
    bb[nt] = base[(size_t)v * 128 + n];
    w2[nt] = W2[n];
    wt[nt] = W1[128 * 128 + n];          // Wt row
  }
  #pragma unroll
  for (int mt = 0; mt < 2; mt++) {
    const int t = 2 * w + mt;            // m>>4 for all 32 rows of this wave/mt
    const float tv = tau[t];
    float ps[4] = {0.f, 0.f, 0.f, 0.f};
    #pragma unroll
    for (int nt = 0; nt < 8; nt++) {
      const float add = bb[nt] + tv * wt[nt];
      f32x4 a4 = acc[mt][nt];
      #pragma unroll
      for (int r = 0; r < 4; r++) {
        float hdn = a4[r] + add;
        hdn = fmaxf(hdn, 0.f);
        ps[r] += hdn * w2[nt];
      }
    }
    // sum across the 16 lanes sharing a quad (xor masks < 16 stay in-group)
    #pragma unroll
    for (int off = 1; off < 16; off <<= 1)
      #pragma unroll
      for (int r = 0; r < 4; r++) ps[r] += __shfl_xor(ps[r], off, 64);
    if (l16 == 0) {
      #pragma unroll
      for (int r = 0; r < 4; r++)
        lOut[32 * w + mt * 16 + quad * 4 + r] = ps[r];
    }
  }
  __syncthreads();
  if (tid < 128) out[(size_t)v * 128 + tid] = lOut[tid] + b2[0];
}

// ---------------------------------------------------------------------------
extern "C" void kernel_launch(void* const* d_in, const int* in_sizes, int n_in,
                              void* d_out, int out_size, void* d_ws, size_t ws_size,
                              hipStream_t stream) {
  const float* h_t      = (const float*)d_in[0];
  const float* messages = (const float*)d_in[1];
  const float* tau      = (const float*)d_in[2];
  const float* theta    = (const float*)d_in[3];
  const float* W1       = (const float*)d_in[4];
  const float* b1       = (const float*)d_in[5];
  const float* W2       = (const float*)d_in[6];
  const float* b2       = (const float*)d_in[7];
  float* out = (float*)d_out;

  // ws layout: [0, VN*128) f32 base | 8192 bf16 Wm^T
  float* base = (float*)d_ws;
  __bf16* wmt = (__bf16*)((char*)d_ws + (size_t)VN * HID * sizeof(float));

  prep_kernel<<<625 + 32, 256, 0, stream>>>(h_t, theta, W1, b1, base, wmt);
  main_kernel<<<VN, 256, 0, stream>>>(messages, tau, W1, W2, b2, base, wmt, out);
}